// Round 1
// 314.431 us; speedup vs baseline: 1.0541x; 1.0541x over previous
//
#include <hip/hip_runtime.h>

#define N_NODES 100000
#define D_SRC 128
#define D_OUT 256
#define K_DIM 256   // D_DST + D_SRC
#define CAP 32      // bucket capacity per node (Poisson(6): P(deg>32) ~ 1e-15)
#define OVF_CAP 2048

typedef __attribute__((ext_vector_type(8))) short short8;
typedef __attribute__((ext_vector_type(4))) float float4v;

__device__ inline unsigned short f2bf(float f) {
    unsigned int u = __float_as_uint(f);
    u += 0x7FFF + ((u >> 16) & 1);   // round-to-nearest-even
    return (unsigned short)(u >> 16);
}
__device__ inline float bf_lo(unsigned int u) { return __uint_as_float(u << 16); }
__device__ inline float bf_hi(unsigned int u) { return __uint_as_float(u & 0xFFFF0000u); }

// ---------------------------------------------------------------------------
// Kernel 1: bucket edges by dst. (unchanged)
// ---------------------------------------------------------------------------
__global__ __launch_bounds__(256) void bucket_kernel(
    const int* __restrict__ ei,     // [2, E]
    int* __restrict__ deg,          // [N] (pre-zeroed)
    int* __restrict__ ovf_cnt,      // [1] (pre-zeroed)
    int* __restrict__ ovf,          // [OVF_CAP*2]
    int* __restrict__ bucket,       // [N*CAP]
    int n_edges)
{
    int e = blockIdx.x * 256 + threadIdx.x;
    if (e >= n_edges) return;
    int s = ei[e];
    int d = ei[n_edges + e];
    int pos = atomicAdd(deg + d, 1);
    if (pos < CAP) {
        bucket[(size_t)d * CAP + pos] = s;
    } else {
        int o = atomicAdd(ovf_cnt, 1);
        if (o < OVF_CAP) { ovf[2 * o] = s; ovf[2 * o + 1] = d; }
    }
}

// ---------------------------------------------------------------------------
// Kernel 2: x_src fp32 -> bf16 linear pack (gather reads this row-major)
// ---------------------------------------------------------------------------
__global__ __launch_bounds__(256) void pack_src_kernel(
    const float* __restrict__ x, unsigned short* __restrict__ xb)
{
    int i = blockIdx.x * 256 + threadIdx.x;   // one float4 each; grid exact
    float4 v = ((const float4*)x)[i];
    ushort4 o;
    o.x = f2bf(v.x); o.y = f2bf(v.y); o.z = f2bf(v.z); o.w = f2bf(v.w);
    ((ushort4*)xb)[i] = o;
}

// ---------------------------------------------------------------------------
// Kernel 3: x_dst fp32 -> bf16 in MFMA-fragment order.
// Granule (16B, 8 bf16) index: ((r>>4)*4 + kc)*64 + (r&15) + 16*sub
// holds x_dst[r][kc*32 + sub*8 + j]. Thread t: r=t>>4, colchunk g=t&15
// (kc=g>>2, sub=g&3). Reads coalesced (16 threads = one 512B row).
// ---------------------------------------------------------------------------
__global__ __launch_bounds__(256) void pack_dst_sw_kernel(
    const float* __restrict__ x, unsigned short* __restrict__ xdsw)
{
    int t = blockIdx.x * 256 + threadIdx.x;   // N_NODES*16 exactly
    int r = t >> 4;
    int g = t & 15;
    const float4* p = (const float4*)(x + (size_t)r * 128 + g * 8);
    float4 v0 = p[0], v1 = p[1];
    union { unsigned short s[8]; short8 v; } pk;
    pk.s[0] = f2bf(v0.x); pk.s[1] = f2bf(v0.y);
    pk.s[2] = f2bf(v0.z); pk.s[3] = f2bf(v0.w);
    pk.s[4] = f2bf(v1.x); pk.s[5] = f2bf(v1.y);
    pk.s[6] = f2bf(v1.z); pk.s[7] = f2bf(v1.w);
    size_t gr = ((size_t)(r >> 4) * 4 + (g >> 2)) * 64 + (r & 15) + ((g & 3) << 4);
    ((short8*)xdsw)[gr] = pk.v;
}

// ---------------------------------------------------------------------------
// Kernel 4: W fp32 -> bf16 in MFMA-fragment order.
// Granule index: ((r>>4)*8 + kc)*64 + (r&15) + 16*sub  (r = out-row, kc=g>>2)
// ---------------------------------------------------------------------------
__global__ __launch_bounds__(256) void convert_w_sw_kernel(
    const float* __restrict__ W, unsigned short* __restrict__ wsw)
{
    int t = blockIdx.x * 256 + threadIdx.x;   // 256*32 = 8192 exactly
    int r = t >> 5;
    int g = t & 31;
    const float4* p = (const float4*)(W + (size_t)r * 256 + g * 8);
    float4 v0 = p[0], v1 = p[1];
    union { unsigned short s[8]; short8 v; } pk;
    pk.s[0] = f2bf(v0.x); pk.s[1] = f2bf(v0.y);
    pk.s[2] = f2bf(v0.z); pk.s[3] = f2bf(v0.w);
    pk.s[4] = f2bf(v1.x); pk.s[5] = f2bf(v1.y);
    pk.s[6] = f2bf(v1.z); pk.s[7] = f2bf(v1.w);
    size_t gr = ((size_t)(r >> 4) * 8 + (g >> 2)) * 64 + (r & 15) + ((g & 3) << 4);
    ((short8*)wsw)[gr] = pk.v;
}

// ---------------------------------------------------------------------------
// Kernel 5: gather-sum over bf16 rows + mean; writes agg directly in
// MFMA-fragment order (one dword per lane, just a retargeted address).
// For lane l (cols 2l,2l+1 of row `node`): kc'=l>>4, l'=(node&15)+16*((l>>2)&3),
// dword slot = l&3.
// ---------------------------------------------------------------------------
__global__ __launch_bounds__(256) void gather_kernel(
    const unsigned short* __restrict__ xsb,  // [N, 128] bf16 linear
    const int*   __restrict__ deg,      // [N]
    const int*   __restrict__ bucket,   // [N*CAP]
    const int*   __restrict__ ovf_cnt,  // [1]
    const int*   __restrict__ ovf,      // [OVF_CAP*2]
    unsigned int* __restrict__ aggsw)   // fragment-order bf16 mean (dwords)
{
    int node = blockIdx.x * 4 + (threadIdx.x >> 6);
    if (node >= N_NODES) return;
    int lane = threadIdx.x & 63;

    int dtot = deg[node];
    int n = (dtot < CAP) ? dtot : CAP;

    int idx = bucket[(size_t)node * CAP + (lane & 31)];

    float ax = 0.f, ay = 0.f;
    int i = 0;
    for (; i + 4 <= n; i += 4) {
        int s0 = __shfl(idx, i);
        int s1 = __shfl(idx, i + 1);
        int s2 = __shfl(idx, i + 2);
        int s3 = __shfl(idx, i + 3);
        unsigned int u0 = ((const unsigned int*)(xsb + (size_t)s0 * D_SRC))[lane];
        unsigned int u1 = ((const unsigned int*)(xsb + (size_t)s1 * D_SRC))[lane];
        unsigned int u2 = ((const unsigned int*)(xsb + (size_t)s2 * D_SRC))[lane];
        unsigned int u3 = ((const unsigned int*)(xsb + (size_t)s3 * D_SRC))[lane];
        ax += bf_lo(u0) + bf_lo(u1) + bf_lo(u2) + bf_lo(u3);
        ay += bf_hi(u0) + bf_hi(u1) + bf_hi(u2) + bf_hi(u3);
    }
    for (; i < n; ++i) {
        int s0 = __shfl(idx, i);
        unsigned int u0 = ((const unsigned int*)(xsb + (size_t)s0 * D_SRC))[lane];
        ax += bf_lo(u0);
        ay += bf_hi(u0);
    }

    if (dtot > CAP) {   // astronomically rare; correctness fallback
        int oc = *ovf_cnt;
        if (oc > OVF_CAP) oc = OVF_CAP;
        for (int o = 0; o < oc; ++o) {
            if (ovf[2 * o + 1] == node) {
                int s0 = ovf[2 * o];
                unsigned int u0 = ((const unsigned int*)(xsb + (size_t)s0 * D_SRC))[lane];
                ax += bf_lo(u0);
                ay += bf_hi(u0);
            }
        }
    }

    float inv = 1.0f / (float)((dtot > 1) ? dtot : 1);
    unsigned int packed = (unsigned int)f2bf(ax * inv)
                        | ((unsigned int)f2bf(ay * inv) << 16);
    size_t dw = ((size_t)(node >> 4) * 4 + (lane >> 4)) * 256
              + (size_t)((node & 15) + 16 * ((lane >> 2) & 3)) * 4 + (lane & 3);
    aggsw[dw] = packed;
}

// ---------------------------------------------------------------------------
// Kernel 6: MFMA GEMM, all operands pre-swizzled to fragment order:
// every main-loop load is a lane-contiguous 1KB wave load (dwordx4/lane).
// Register double-buffer: loads for kc+1 issue before MFMAs of kc.
// Epilogue: wave-private LDS slice, wave-local lgkmcnt waits (no barriers).
// ---------------------------------------------------------------------------
__global__ __launch_bounds__(256) void mfma_gemm_kernel(
    const short8* __restrict__ xdsw,   // [N/16][4][64] granules
    const short8* __restrict__ aggsw,  // [N/16][4][64] granules
    const short8* __restrict__ wsw,    // [16][8][64] granules
    const float* __restrict__ bias,    // [256]
    float*       __restrict__ out)     // [N, 256] fp32
{
    __shared__ float eps[4][16][68];   // [wave][row][col64 + pad4]

    int wave = threadIdx.x >> 6;  // column block n0 = wave*64
    int lane = threadIdx.x & 63;
    int lrow = lane & 15;
    int kq   = lane >> 4;
    int mb   = blockIdx.x;        // 64-row tile
    int m0   = mb * 64;
    int n0   = wave * 64;

    // validity is uniform per 16-row fragment (N_NODES % 16 == 0)
    bool mok[4];
    #pragma unroll
    for (int mf = 0; mf < 4; ++mf) mok[mf] = (m0 + mf * 16) < N_NODES;

    const short8* Ax = xdsw  + (size_t)mb * 1024 + lane;  // + mf*256 + kc*64
    const short8* Ag = aggsw + (size_t)mb * 1024 + lane;  // + mf*256 + kc'*64
    const short8* Bw = wsw   + (size_t)wave * 2048 + lane; // + nf*512 + kc*64

    float4v acc[4][4];
    #pragma unroll
    for (int i = 0; i < 4; ++i)
        #pragma unroll
        for (int j = 0; j < 4; ++j)
            acc[i][j] = (float4v){0.f, 0.f, 0.f, 0.f};

    const short8 zfrag = (short8){0,0,0,0,0,0,0,0};
    short8 a[2][4], b[2][4];

    #pragma unroll
    for (int mf = 0; mf < 4; ++mf)
        a[0][mf] = mok[mf] ? Ax[mf * 256] : zfrag;
    #pragma unroll
    for (int nf = 0; nf < 4; ++nf)
        b[0][nf] = Bw[nf * 512];

    #pragma unroll
    for (int kc = 0; kc < 8; ++kc) {
        const int cur = kc & 1, nxt = cur ^ 1;
        if (kc < 7) {
            const int k1 = kc + 1;
            const short8* A = (k1 < 4) ? Ax : Ag;
            const int kk = (k1 < 4) ? k1 : (k1 - 4);
            #pragma unroll
            for (int mf = 0; mf < 4; ++mf)
                a[nxt][mf] = mok[mf] ? A[mf * 256 + kk * 64] : zfrag;
            #pragma unroll
            for (int nf = 0; nf < 4; ++nf)
                b[nxt][nf] = Bw[nf * 512 + k1 * 64];
        }
        #pragma unroll
        for (int mf = 0; mf < 4; ++mf)
            #pragma unroll
            for (int nf = 0; nf < 4; ++nf)
                acc[mf][nf] = __builtin_amdgcn_mfma_f32_16x16x32_bf16(
                    a[cur][mf], b[cur][nf], acc[mf][nf], 0, 0, 0);
    }

    // ---- epilogue: bias+relu, wave-private LDS bounce, 256B stores ----
    float bv[4];
    #pragma unroll
    for (int nf = 0; nf < 4; ++nf)
        bv[nf] = bias[n0 + nf * 16 + lrow];

    int srow   = lane >> 4;     // 0..3
    int schunk = lane & 15;     // 16B units across 64 cols

    #pragma unroll
    for (int mf = 0; mf < 4; ++mf) {
        if (!mok[mf]) continue;   // block-uniform
        #pragma unroll
        for (int nf = 0; nf < 4; ++nf)
            #pragma unroll
            for (int r = 0; r < 4; ++r)
                eps[wave][kq * 4 + r][nf * 16 + lrow] =
                    fmaxf(acc[mf][nf][r] + bv[nf], 0.f);
        // wave-private slice: wave-local LDS drain instead of __syncthreads
        asm volatile("s_waitcnt lgkmcnt(0)" ::: "memory");
        #pragma unroll
        for (int c = 0; c < 4; ++c) {
            int row  = c * 4 + srow;
            float4 v = *(const float4*)&eps[wave][row][schunk * 4];
            int grow = m0 + mf * 16 + row;
            *(float4*)(out + (size_t)grow * D_OUT + n0 + schunk * 4) = v;
        }
        asm volatile("s_waitcnt lgkmcnt(0)" ::: "memory");
    }
}

extern "C" void kernel_launch(void* const* d_in, const int* in_sizes, int n_in,
                              void* d_out, int out_size, void* d_ws, size_t ws_size,
                              hipStream_t stream) {
    const float* x_src = (const float*)d_in[0];
    const float* x_dst = (const float*)d_in[1];
    const int*   ei    = (const int*)d_in[2];
    const float* W     = (const float*)d_in[3];
    const float* bias  = (const float*)d_in[4];
    float* out = (float*)d_out;

    int n_edges = in_sizes[2] / 2;

    // workspace layout (ws):
    //   deg    : N_NODES int           (zeroed)
    //   ovf_cnt: 4 int                 (zeroed [0])
    //   ovf    : OVF_CAP*2 int
    //   wsw    : 256*256 ushort  (bf16 W, fragment order)
    //   aggsw  : N/16*4*64*8 ushort (bf16 agg, fragment order)
    //   xdsw   : N/16*4*64*8 ushort (bf16 x_dst, fragment order)
    int* deg     = (int*)d_ws;
    int* ovf_cnt = deg + N_NODES;
    int* ovf     = ovf_cnt + 4;
    unsigned short* wsw   = (unsigned short*)(ovf + OVF_CAP * 2);
    unsigned short* aggsw = wsw + (size_t)D_OUT * K_DIM;
    unsigned short* xdsw  = aggsw + (size_t)(N_NODES / 16) * 4 * 64 * 8;

    // d_out doubles as stream-ordered scratch for buffers that are dead
    // before the GEMM (which overwrites all of out):
    //   bucket : N_NODES*CAP int   at offset 0        (12.8 MB)
    //   xsb    : N_NODES*128 ushort at 12.8 MB        (25.6 MB)
    int* bucket = (int*)d_out;
    unsigned short* xsb = (unsigned short*)(bucket + (size_t)N_NODES * CAP);

    hipMemsetAsync(d_ws, 0, (N_NODES + 4) * sizeof(int), stream);

    bucket_kernel<<<(n_edges + 255) / 256, 256, 0, stream>>>(
        ei, deg, ovf_cnt, ovf, bucket, n_edges);

    pack_src_kernel<<<(N_NODES * D_SRC / 4) / 256, 256, 0, stream>>>(x_src, xsb);

    pack_dst_sw_kernel<<<(N_NODES * 16) / 256, 256, 0, stream>>>(x_dst, xdsw);

    convert_w_sw_kernel<<<(D_OUT * K_DIM / 8) / 256, 256, 0, stream>>>(W, wsw);

    gather_kernel<<<(N_NODES + 3) / 4, 256, 0, stream>>>(
        xsb, deg, bucket, ovf_cnt, ovf, (unsigned int*)aggsw);

    mfma_gemm_kernel<<<(N_NODES + 63) / 64, 256, 0, stream>>>(
        (const short8*)xdsw, (const short8*)aggsw, (const short8*)wsw, bias, out);
}